// Round 12
// baseline (704.656 us; speedup 1.0000x reference)
//
#include <hip/hip_runtime.h>
#include <math.h>

// ---------------------------------------------------------------------------
// FraudDetectionGCN: 3x GCNConv(relu) + FC + log_softmax.
// R12 change vs R11 — CSR build was ~120us (biggest block): hist/scatter ran
// at 196 blocks (~3 waves/CU, undersubscribed) and bucket_csr wasted 15.5KB
// LDS staging. Now:
//  * hist: CHUNK 2048 -> 782 blocks, LDS pre-agg.
//  * scatter: single-pass global atomicAdd slot reservation (1024 counters,
//    ~1.5k ops each, L2-serialized ~free); pairs writes stay L2-dense.
//  * bucket_csr: direct col write at atomicAdd'd position (bucket-local 8KB
//    region -> L2 absorbs); LDS 1.5KB -> full occupancy.
// agg: bf16 g rows (bytes-bound at ~3.6TB/s random-gather fabric ceiling).
// norm factorization: out[n] = dinv[n]*(sum_{s->n} g[s] + g[n]) + b,
// where g = dinv[:,None] * (h @ W), quantized to bf16.
// ---------------------------------------------------------------------------

static inline size_t alignup(size_t x){ return (x + 511) & ~size_t(511); }

typedef float v4f __attribute__((ext_vector_type(4)));
typedef unsigned short v4u16 __attribute__((ext_vector_type(4)));

__device__ __forceinline__ unsigned short f32_to_bf16(float f){
  union { float f; unsigned int u; } c; c.f = f;
  unsigned int u = c.u + 0x7FFFu + ((c.u >> 16) & 1u);   // round-nearest-even
  return (unsigned short)(u >> 16);
}
__device__ __forceinline__ v4f bf16x4_to_f32(v4u16 a){
  union { unsigned int u; float f; } c0,c1,c2,c3;
  c0.u = (unsigned int)a.x << 16;
  c1.u = (unsigned int)a.y << 16;
  c2.u = (unsigned int)a.z << 16;
  c3.u = (unsigned int)a.w << 16;
  v4f r; r.x=c0.f; r.y=c1.f; r.z=c2.f; r.w=c3.f;
  return r;
}

#define NBUCK 1024          // histogram bins (dst>>7); 782 used at N=100k
#define CHUNK 2048          // edges per block in hist/scatter (782 blocks)
#define CCAP  3584          // max edges per bucket (mean ~2046, +30 sigma)

__global__ void zero_kernel(int* __restrict__ p, int n){
  int i = blockIdx.x*256 + threadIdx.x;
  if(i<n) p[i] = 0;
}

// Pass A: global histogram of dst>>7 (LDS-aggregated, 782 blocks).
__global__ __launch_bounds__(256) void hist_kernel(const int* __restrict__ dst,
                                                   int* __restrict__ bcnt, int E){
  __shared__ int h[NBUCK];
  int t = threadIdx.x;
  for(int i=t;i<NBUCK;i+=256) h[i]=0;
  __syncthreads();
  int base = blockIdx.x*CHUNK;
  #pragma unroll
  for(int i=0;i<CHUNK;i+=256){
    int e = base+i+t;
    if(e<E) atomicAdd(&h[dst[e]>>7], 1);
  }
  __syncthreads();
  for(int i=t;i<NBUCK;i+=256) if(h[i]) atomicAdd(&bcnt[i], h[i]);
}

// Exclusive scan of 1024 bucket counts (single block). bbase = bfill = prefix.
__global__ void scan_buckets_kernel(const int* __restrict__ bcnt, int* __restrict__ bbase,
                                    int* __restrict__ bfill){
  __shared__ int sh[256];
  int t = threadIdx.x;
  int v0=bcnt[4*t], v1=bcnt[4*t+1], v2=bcnt[4*t+2], v3=bcnt[4*t+3];
  int ts = v0+v1+v2+v3;
  sh[t]=ts; __syncthreads();
  for(int off=1; off<256; off<<=1){
    int x=(t>=off)?sh[t-off]:0; __syncthreads();
    sh[t]+=x; __syncthreads();
  }
  int run = sh[t]-ts;
  int i0=4*t;
  bbase[i0+0]=run; bfill[i0+0]=run; run+=v0;
  bbase[i0+1]=run; bfill[i0+1]=run; run+=v1;
  bbase[i0+2]=run; bfill[i0+2]=run; run+=v2;
  bbase[i0+3]=run; bfill[i0+3]=run;
}

// Pass B: scatter packed (local_dst<<17 | src) into bucket regions.
// Slot reservation by direct global atomicAdd (1024 counters; per-bucket
// write stream stays spatially dense -> L2 absorbs the 4B scatter).
__global__ __launch_bounds__(256) void scatter_kernel(const int* __restrict__ src,
                                                      const int* __restrict__ dst,
                                                      int* __restrict__ bfill,
                                                      int* __restrict__ pairs, int E){
  int base = blockIdx.x*CHUNK + threadIdx.x;
  #pragma unroll
  for(int i=0;i<CHUNK;i+=256){
    int e = base+i;
    if(e<E){
      int d = dst[e];
      int slot = atomicAdd(&bfill[d>>7], 1);
      pairs[slot] = ((d&127)<<17) | src[e];
    }
  }
}

// Pass C: one block per bucket (128 dst nodes). LDS counting sort (1.5KB) ->
// row_ptr, dinv; col written directly at its final position (bucket-local
// 8KB region -> L2-absorbed randomness).
__global__ __launch_bounds__(256) void bucket_csr_kernel(const int* __restrict__ pairs,
                                                         const int* __restrict__ bbase,
                                                         int* __restrict__ row_ptr,
                                                         float* __restrict__ dinv,
                                                         int* __restrict__ col,
                                                         int N, int E){
  __shared__ int hist[128];
  __shared__ int pref[128];
  __shared__ int fill[128];
  int b = blockIdx.x, t = threadIdx.x;
  int s = bbase[b], e = bbase[b+1];
  int cnt = e - s; if(cnt > CCAP) cnt = CCAP;   // unreachable guard
  if(t<128) hist[t]=0;
  __syncthreads();
  int v[CCAP/256];
  #pragma unroll
  for(int i=0;i<CCAP/256;i++){
    int idx = i*256 + t;
    if(idx<cnt){ v[i]=pairs[s+idx]; atomicAdd(&hist[v[i]>>17], 1); }
  }
  __syncthreads();
  if(t<128) pref[t]=hist[t];
  __syncthreads();
  for(int off=1; off<128; off<<=1){
    int x=0;
    if(t<128 && t>=off) x=pref[t-off];
    __syncthreads();
    if(t<128) pref[t]+=x;
    __syncthreads();
  }
  if(t<128){
    int ex = pref[t]-hist[t];                 // exclusive prefix
    fill[t] = s + ex;
    int node = b*128 + t;
    if(node<N){
      row_ptr[node] = s + ex;
      dinv[node] = rsqrtf((float)(hist[t]+1)); // +1 self loop
    }
  }
  if(b==0 && t==0) row_ptr[N]=E;
  __syncthreads();
  #pragma unroll
  for(int i=0;i<CCAP/256;i++){
    int idx = i*256 + t;
    if(idx<cnt){
      int ld = v[i]>>17;
      int pos = atomicAdd(&fill[ld], 1);
      col[pos] = v[i] & 0x1FFFF;
    }
  }
}

// g[n,:] = bf16( dinv[n] * (h[n,:K] @ W[K,64]) ).
// LDS-staged: TR=32 rows staged with coalesced float4 loads; each of the
// 4 waves computes RW=8 rows; k-loop unroll capped at 2 (R7 spill lesson).
template<int K>
__global__ __launch_bounds__(256) void lin_kernel(const float* __restrict__ h,
                                                  const float* __restrict__ W,
                                                  const float* __restrict__ dinv,
                                                  unsigned short* __restrict__ g, int N){
  constexpr int TR = 32, RW = 8;
  __shared__ __align__(16) float hs[TR*K];
  int t = threadIdx.x, wave = t>>6, lane = t&63;
  long rbase = (long)blockIdx.x*TR;
  const v4f* hsrc = (const v4f*)(h + rbase*K);
  if(rbase + TR <= N){
    #pragma unroll
    for(int idx = t; idx < TR*K/4; idx += 256)
      ((v4f*)hs)[idx] = hsrc[idx];
  } else {
    int lim = (int)((N - rbase)*K/4);            // tail block
    for(int idx = t; idx < lim; idx += 256)
      ((v4f*)hs)[idx] = hsrc[idx];
  }
  __syncthreads();
  float acc[RW];
  #pragma unroll
  for(int r=0;r<RW;r++) acc[r]=0.f;
  const float* hw = hs + wave*RW*K;
  #pragma unroll 2
  for(int k=0;k<K;k+=4){
    float w0 = W[(k+0)*64+lane];
    float w1 = W[(k+1)*64+lane];
    float w2 = W[(k+2)*64+lane];
    float w3 = W[(k+3)*64+lane];
    #pragma unroll
    for(int r=0;r<RW;r++){
      v4f hv = *(const v4f*)&hw[r*K+k];
      acc[r] = fmaf(hv.w, w3, fmaf(hv.z, w2, fmaf(hv.y, w1, fmaf(hv.x, w0, acc[r]))));
    }
  }
  long row0 = rbase + wave*RW;
  #pragma unroll
  for(int r=0;r<RW;r++){
    if(row0 + r < N)
      g[(row0+r)*64 + lane] = f32_to_bf16(dinv[row0+r]*acc[r]);
  }
}

// Gather for 4-nodes-per-wave layout over bf16 g rows (128B each):
// lane = 16*q + l; group q handles node n, lane carries features [4l,4l+4).
// All 16 edges of a chunk processed (masked, clamped-to-self) so all loads
// issue back-to-back; fp32 accumulate.
__device__ __forceinline__ v4f gather_row4(const unsigned short* __restrict__ g,
                                           const int* __restrict__ col,
                                           int n, int s, int e, int l){
  v4f acc = bf16x4_to_f32(*(const v4u16*)&g[(size_t)n*64 + l*4]);   // self
  for(int i = s; i < e; i += 16){
    int rem = e - i;                               // group-uniform
    int myc = (l < rem) ? col[i + l] : n;
    #pragma unroll
    for(int j0 = 0; j0 < 16; j0 += 4){
      int c0 = __shfl(myc, j0+0, 16);
      int c1 = __shfl(myc, j0+1, 16);
      int c2 = __shfl(myc, j0+2, 16);
      int c3 = __shfl(myc, j0+3, 16);
      v4f x0 = bf16x4_to_f32(*(const v4u16*)&g[(size_t)c0*64 + l*4]);
      v4f x1 = bf16x4_to_f32(*(const v4u16*)&g[(size_t)c1*64 + l*4]);
      v4f x2 = bf16x4_to_f32(*(const v4u16*)&g[(size_t)c2*64 + l*4]);
      v4f x3 = bf16x4_to_f32(*(const v4u16*)&g[(size_t)c3*64 + l*4]);
      float m0 = (j0+0 < rem) ? 1.f : 0.f;
      float m1 = (j0+1 < rem) ? 1.f : 0.f;
      float m2 = (j0+2 < rem) ? 1.f : 0.f;
      float m3 = (j0+3 < rem) ? 1.f : 0.f;
      acc.x = fmaf(m0,x0.x, fmaf(m1,x1.x, fmaf(m2,x2.x, fmaf(m3,x3.x, acc.x))));
      acc.y = fmaf(m0,x0.y, fmaf(m1,x1.y, fmaf(m2,x2.y, fmaf(m3,x3.y, acc.y))));
      acc.z = fmaf(m0,x0.z, fmaf(m1,x1.z, fmaf(m2,x2.z, fmaf(m3,x3.z, acc.z))));
      acc.w = fmaf(m0,x0.w, fmaf(m1,x1.w, fmaf(m2,x2.w, fmaf(m3,x3.w, acc.w))));
    }
  }
  return acc;
}

// h[n,:] = relu(dinv[n]*gather + bias). 4 nodes/wave, v4f stores.
__global__ __launch_bounds__(256) void agg_kernel(const unsigned short* __restrict__ g,
                                                  const int* __restrict__ row_ptr,
                                                  const int* __restrict__ col,
                                                  const float* __restrict__ dinv,
                                                  const float* __restrict__ bias,
                                                  float* __restrict__ h, int N){
  int t = threadIdx.x, wave = t>>6, lane = t&63;
  int l = lane & 15, q = lane >> 4;
  int n = blockIdx.x*16 + wave*4 + q;
  bool valid = n < N;
  if(!valid) n = N-1;
  int s = row_ptr[n], e = row_ptr[n+1];
  v4f acc = gather_row4(g, col, n, s, e, l);
  if(valid){
    float dv = dinv[n];
    v4f bs = *(const v4f*)&bias[l*4];
    v4f r;
    r.x = fmaxf(fmaf(dv, acc.x, bs.x), 0.f);
    r.y = fmaxf(fmaf(dv, acc.y, bs.y), 0.f);
    r.z = fmaxf(fmaf(dv, acc.z, bs.z), 0.f);
    r.w = fmaxf(fmaf(dv, acc.w, bs.w), 0.f);
    *(v4f*)&h[(size_t)n*64 + l*4] = r;
  }
}

// Layer-3 agg with fused FC + log_softmax epilogue: never materializes h3.
__global__ __launch_bounds__(256) void agg_final_kernel(const unsigned short* __restrict__ g,
                                                        const int* __restrict__ row_ptr,
                                                        const int* __restrict__ col,
                                                        const float* __restrict__ dinv,
                                                        const float* __restrict__ bias,
                                                        const float* __restrict__ Wfc,
                                                        const float* __restrict__ bfc,
                                                        float* __restrict__ out, int N){
  int t = threadIdx.x, wave = t>>6, lane = t&63;
  int l = lane & 15, q = lane >> 4;
  int n = blockIdx.x*16 + wave*4 + q;
  bool valid = n < N;
  if(!valid) n = N-1;
  int s = row_ptr[n], e = row_ptr[n+1];
  v4f acc = gather_row4(g, col, n, s, e, l);
  float dv = dinv[n];
  v4f bs = *(const v4f*)&bias[l*4];
  v4f hv;
  hv.x = fmaxf(fmaf(dv, acc.x, bs.x), 0.f);
  hv.y = fmaxf(fmaf(dv, acc.y, bs.y), 0.f);
  hv.z = fmaxf(fmaf(dv, acc.z, bs.z), 0.f);
  hv.w = fmaxf(fmaf(dv, acc.w, bs.w), 0.f);
  // Wfc row-major [64][2]: lane l covers features 4l..4l+3 -> 8 floats at 8l.
  v4f wa = *(const v4f*)&Wfc[l*8];
  v4f wb = *(const v4f*)&Wfc[l*8+4];
  float p0 = hv.x*wa.x + hv.y*wa.z + hv.z*wb.x + hv.w*wb.z;
  float p1 = hv.x*wa.y + hv.y*wa.w + hv.z*wb.y + hv.w*wb.w;
  for(int off=8; off; off>>=1){
    p0 += __shfl_down(p0, off, 16);
    p1 += __shfl_down(p1, off, 16);
  }
  if(valid && l==0){
    float l0 = p0 + bfc[0], l1 = p1 + bfc[1];
    float m  = fmaxf(l0, l1);
    float lse = m + logf(expf(l0-m) + expf(l1-m));
    out[(size_t)n*2+0] = l0 - lse;
    out[(size_t)n*2+1] = l1 - lse;
  }
}

extern "C" void kernel_launch(void* const* d_in, const int* in_sizes, int n_in,
                              void* d_out, int out_size, void* d_ws, size_t ws_size,
                              hipStream_t stream) {
  (void)n_in; (void)out_size; (void)ws_size;
  const float* x   = (const float*)d_in[0];
  const int*   ei  = (const int*)  d_in[1];
  const float* W1  = (const float*)d_in[2];
  const float* b1  = (const float*)d_in[3];
  const float* W2  = (const float*)d_in[4];
  const float* b2  = (const float*)d_in[5];
  const float* W3  = (const float*)d_in[6];
  const float* b3  = (const float*)d_in[7];
  const float* Wfc = (const float*)d_in[8];
  const float* bfc = (const float*)d_in[9];
  float* out = (float*)d_out;

  const int N = in_sizes[0] / 128;   // 100000
  const int E = in_sizes[1] / 2;     // 1600000
  const int* src = ei;
  const int* dst = ei + E;
  const int NB = (N + 127) / 128;    // 782 buckets

  // ---- workspace carve ----
  char* w = (char*)d_ws;
  int*   bcnt    = (int*)  w; w += alignup((size_t)NBUCK*4);
  int*   bbase   = (int*)  w; w += alignup((size_t)(NBUCK+1)*4);
  int*   bfill   = (int*)  w; w += alignup((size_t)NBUCK*4);
  int*   pairs   = (int*)  w; w += alignup((size_t)E*4);
  int*   row_ptr = (int*)  w; w += alignup((size_t)(N+1)*4);
  float* dinv    = (float*)w; w += alignup((size_t)N*4);
  int*   col     = (int*)  w; w += alignup((size_t)E*4);
  unsigned short* bufA = (unsigned short*)w; w += alignup((size_t)N*64*2); // bf16 g
  float* bufB    = (float*)w; w += alignup((size_t)N*64*4);                // fp32 h

  const int nblkE   = (E + CHUNK - 1) / CHUNK;   // 782
  const int nblkLin = (N + 31) / 32;             // TR=32 -> 3125 (exact)
  const int nblkAgg = (N + 15) / 16;             // 4 nodes/wave, 4 waves/blk

  // ---- CSR build ----
  zero_kernel<<<(NBUCK+255)/256, 256, 0, stream>>>(bcnt, NBUCK);
  hist_kernel<<<nblkE, 256, 0, stream>>>(dst, bcnt, E);
  scan_buckets_kernel<<<1, 256, 0, stream>>>(bcnt, bbase, bfill);
  scatter_kernel<<<nblkE, 256, 0, stream>>>(src, dst, bfill, pairs, E);
  bucket_csr_kernel<<<NB, 256, 0, stream>>>(pairs, bbase, row_ptr, dinv, col, N, E);

  // ---- layer 1: x[N,128] ----
  lin_kernel<128><<<nblkLin, 256, 0, stream>>>(x, W1, dinv, bufA, N);
  agg_kernel<<<nblkAgg, 256, 0, stream>>>(bufA, row_ptr, col, dinv, b1, bufB, N);
  // ---- layer 2 ----
  lin_kernel<64><<<nblkLin, 256, 0, stream>>>(bufB, W2, dinv, bufA, N);
  agg_kernel<<<nblkAgg, 256, 0, stream>>>(bufA, row_ptr, col, dinv, b2, bufB, N);
  // ---- layer 3 + FC + log_softmax (fused) ----
  lin_kernel<64><<<nblkLin, 256, 0, stream>>>(bufB, W3, dinv, bufA, N);
  agg_final_kernel<<<nblkAgg, 256, 0, stream>>>(bufA, row_ptr, col, dinv, b3,
                                                Wfc, bfc, out, N);
}

// Round 13
// 325.799 us; speedup vs baseline: 2.1629x; 2.1629x over previous
//
#include <hip/hip_runtime.h>
#include <math.h>

// ---------------------------------------------------------------------------
// FraudDetectionGCN: 3x GCNConv(relu) + FC + log_softmax.
// R13 changes vs R12:
//  * scatter REVERTED to R11's two-phase LDS reservation (R12's single-pass
//    global atomics = 1562 serialized device-scope RMWs per counter = 379us).
//    LDS-aggregate first; only 196 global atomics per bucket.
//  * lin64 kernels FUSED into the preceding agg: h row stays in registers ->
//    4KB LDS stage -> one barrier -> g_next = bf16(dinv*(h@W_next)) with
//    lane=output-feature (coalesced L1-hit W reads, LDS broadcast h reads).
//    h never touches global memory; 2 launches + 51MB traffic removed.
//    Matmul VALU hides under the memory-bound gather.
// agg: bf16 g rows (bytes-bound at ~3.6TB/s random-gather fabric ceiling).
// norm factorization: out[n] = dinv[n]*(sum_{s->n} g[s] + g[n]) + b,
// where g = dinv[:,None] * (h @ W), quantized to bf16.
// ---------------------------------------------------------------------------

static inline size_t alignup(size_t x){ return (x + 511) & ~size_t(511); }

typedef float v4f __attribute__((ext_vector_type(4)));
typedef unsigned short v4u16 __attribute__((ext_vector_type(4)));

__device__ __forceinline__ unsigned short f32_to_bf16(float f){
  union { float f; unsigned int u; } c; c.f = f;
  unsigned int u = c.u + 0x7FFFu + ((c.u >> 16) & 1u);   // round-nearest-even
  return (unsigned short)(u >> 16);
}
__device__ __forceinline__ v4f bf16x4_to_f32(v4u16 a){
  union { unsigned int u; float f; } c0,c1,c2,c3;
  c0.u = (unsigned int)a.x << 16;
  c1.u = (unsigned int)a.y << 16;
  c2.u = (unsigned int)a.z << 16;
  c3.u = (unsigned int)a.w << 16;
  v4f r; r.x=c0.f; r.y=c1.f; r.z=c2.f; r.w=c3.f;
  return r;
}

#define NBUCK 1024          // histogram bins (dst>>7); 782 used at N=100k
#define CHUNK 8192          // edges per block in hist/scatter (196 blocks)
#define CCAP  3584          // max edges per bucket (mean ~2046, +30 sigma)

__global__ void zero_kernel(int* __restrict__ p, int n){
  int i = blockIdx.x*256 + threadIdx.x;
  if(i<n) p[i] = 0;
}

// Pass A: global histogram of dst>>7 (LDS-aggregated).
__global__ __launch_bounds__(256) void hist_kernel(const int* __restrict__ dst,
                                                   int* __restrict__ bcnt, int E){
  __shared__ int h[NBUCK];
  int t = threadIdx.x;
  for(int i=t;i<NBUCK;i+=256) h[i]=0;
  __syncthreads();
  int base = blockIdx.x*CHUNK;
  #pragma unroll 4
  for(int i=0;i<CHUNK;i+=256){
    int e = base+i+t;
    if(e<E) atomicAdd(&h[dst[e]>>7], 1);
  }
  __syncthreads();
  for(int i=t;i<NBUCK;i+=256) if(h[i]) atomicAdd(&bcnt[i], h[i]);
}

// Exclusive scan of 1024 bucket counts (single block). bbase = bfill = prefix.
__global__ void scan_buckets_kernel(const int* __restrict__ bcnt, int* __restrict__ bbase,
                                    int* __restrict__ bfill){
  __shared__ int sh[256];
  int t = threadIdx.x;
  int v0=bcnt[4*t], v1=bcnt[4*t+1], v2=bcnt[4*t+2], v3=bcnt[4*t+3];
  int ts = v0+v1+v2+v3;
  sh[t]=ts; __syncthreads();
  for(int off=1; off<256; off<<=1){
    int x=(t>=off)?sh[t-off]:0; __syncthreads();
    sh[t]+=x; __syncthreads();
  }
  int run = sh[t]-ts;
  int i0=4*t;
  bbase[i0+0]=run; bfill[i0+0]=run; run+=v0;
  bbase[i0+1]=run; bfill[i0+1]=run; run+=v1;
  bbase[i0+2]=run; bfill[i0+2]=run; run+=v2;
  bbase[i0+3]=run; bfill[i0+3]=run;
}

// Pass B: scatter packed (local_dst<<17 | src) into bucket regions.
// Two-phase: LDS histogram, ONE global atomic per nonzero bucket per block
// (196 max per counter — R12's per-edge global atomics were 1562/counter
// serialized device-scope RMWs = 379us), then LDS slot counters.
__global__ __launch_bounds__(256) void scatter_kernel(const int* __restrict__ src,
                                                      const int* __restrict__ dst,
                                                      int* __restrict__ bfill,
                                                      int* __restrict__ pairs, int E){
  __shared__ int h[NBUCK];
  __shared__ int base[NBUCK];
  int t = threadIdx.x;
  for(int i=t;i<NBUCK;i+=256) h[i]=0;
  __syncthreads();
  int cbase = blockIdx.x*CHUNK;
  int d[CHUNK/256];
  #pragma unroll
  for(int i=0;i<CHUNK/256;i++){
    int e = cbase+i*256+t;
    d[i] = (e<E) ? dst[e] : -1;
    if(d[i]>=0) atomicAdd(&h[d[i]>>7], 1);
  }
  __syncthreads();
  for(int i=t;i<NBUCK;i+=256) base[i] = h[i] ? atomicAdd(&bfill[i], h[i]) : 0;
  __syncthreads();
  #pragma unroll
  for(int i=0;i<CHUNK/256;i++){
    int e = cbase+i*256+t;
    if(d[i]>=0){
      int b = d[i]>>7;
      int slot = atomicAdd(&base[b], 1);
      pairs[slot] = ((d[i]&127)<<17) | src[e];
    }
  }
}

// Pass C: one block per bucket (128 dst nodes). LDS counting sort (1.5KB) ->
// row_ptr, dinv; col written directly at final position (bucket-local 8KB
// region -> L2-absorbed randomness).
__global__ __launch_bounds__(256) void bucket_csr_kernel(const int* __restrict__ pairs,
                                                         const int* __restrict__ bbase,
                                                         int* __restrict__ row_ptr,
                                                         float* __restrict__ dinv,
                                                         int* __restrict__ col,
                                                         int N, int E){
  __shared__ int hist[128];
  __shared__ int pref[128];
  __shared__ int fill[128];
  int b = blockIdx.x, t = threadIdx.x;
  int s = bbase[b], e = bbase[b+1];
  int cnt = e - s; if(cnt > CCAP) cnt = CCAP;   // unreachable guard
  if(t<128) hist[t]=0;
  __syncthreads();
  int v[CCAP/256];
  #pragma unroll
  for(int i=0;i<CCAP/256;i++){
    int idx = i*256 + t;
    if(idx<cnt){ v[i]=pairs[s+idx]; atomicAdd(&hist[v[i]>>17], 1); }
  }
  __syncthreads();
  if(t<128) pref[t]=hist[t];
  __syncthreads();
  for(int off=1; off<128; off<<=1){
    int x=0;
    if(t<128 && t>=off) x=pref[t-off];
    __syncthreads();
    if(t<128) pref[t]+=x;
    __syncthreads();
  }
  if(t<128){
    int ex = pref[t]-hist[t];                 // exclusive prefix
    fill[t] = s + ex;
    int node = b*128 + t;
    if(node<N){
      row_ptr[node] = s + ex;
      dinv[node] = rsqrtf((float)(hist[t]+1)); // +1 self loop
    }
  }
  if(b==0 && t==0) row_ptr[N]=E;
  __syncthreads();
  #pragma unroll
  for(int i=0;i<CCAP/256;i++){
    int idx = i*256 + t;
    if(idx<cnt){
      int ld = v[i]>>17;
      int pos = atomicAdd(&fill[ld], 1);
      col[pos] = v[i] & 0x1FFFF;
    }
  }
}

// g[n,:] = bf16( dinv[n] * (h[n,:K] @ W[K,64]) ).  Used for layer 1 only.
// LDS-staged: TR=32 rows with coalesced float4 loads; 4 waves x RW=8 rows;
// k-loop unroll capped at 2 (R7 spill lesson).
template<int K>
__global__ __launch_bounds__(256) void lin_kernel(const float* __restrict__ h,
                                                  const float* __restrict__ W,
                                                  const float* __restrict__ dinv,
                                                  unsigned short* __restrict__ g, int N){
  constexpr int TR = 32, RW = 8;
  __shared__ __align__(16) float hs[TR*K];
  int t = threadIdx.x, wave = t>>6, lane = t&63;
  long rbase = (long)blockIdx.x*TR;
  const v4f* hsrc = (const v4f*)(h + rbase*K);
  if(rbase + TR <= N){
    #pragma unroll
    for(int idx = t; idx < TR*K/4; idx += 256)
      ((v4f*)hs)[idx] = hsrc[idx];
  } else {
    int lim = (int)((N - rbase)*K/4);            // tail block
    for(int idx = t; idx < lim; idx += 256)
      ((v4f*)hs)[idx] = hsrc[idx];
  }
  __syncthreads();
  float acc[RW];
  #pragma unroll
  for(int r=0;r<RW;r++) acc[r]=0.f;
  const float* hw = hs + wave*RW*K;
  #pragma unroll 2
  for(int k=0;k<K;k+=4){
    float w0 = W[(k+0)*64+lane];
    float w1 = W[(k+1)*64+lane];
    float w2 = W[(k+2)*64+lane];
    float w3 = W[(k+3)*64+lane];
    #pragma unroll
    for(int r=0;r<RW;r++){
      v4f hv = *(const v4f*)&hw[r*K+k];
      acc[r] = fmaf(hv.w, w3, fmaf(hv.z, w2, fmaf(hv.y, w1, fmaf(hv.x, w0, acc[r]))));
    }
  }
  long row0 = rbase + wave*RW;
  #pragma unroll
  for(int r=0;r<RW;r++){
    if(row0 + r < N)
      g[(row0+r)*64 + lane] = f32_to_bf16(dinv[row0+r]*acc[r]);
  }
}

// Gather for 4-nodes-per-wave layout over bf16 g rows (128B each):
// lane = 16*q + l; group q handles node n, lane carries features [4l,4l+4).
// All 16 edges of a chunk processed (masked, clamped-to-self); fp32 accum.
__device__ __forceinline__ v4f gather_row4(const unsigned short* __restrict__ g,
                                           const int* __restrict__ col,
                                           int n, int s, int e, int l){
  v4f acc = bf16x4_to_f32(*(const v4u16*)&g[(size_t)n*64 + l*4]);   // self
  for(int i = s; i < e; i += 16){
    int rem = e - i;                               // group-uniform
    int myc = (l < rem) ? col[i + l] : n;
    #pragma unroll
    for(int j0 = 0; j0 < 16; j0 += 4){
      int c0 = __shfl(myc, j0+0, 16);
      int c1 = __shfl(myc, j0+1, 16);
      int c2 = __shfl(myc, j0+2, 16);
      int c3 = __shfl(myc, j0+3, 16);
      v4f x0 = bf16x4_to_f32(*(const v4u16*)&g[(size_t)c0*64 + l*4]);
      v4f x1 = bf16x4_to_f32(*(const v4u16*)&g[(size_t)c1*64 + l*4]);
      v4f x2 = bf16x4_to_f32(*(const v4u16*)&g[(size_t)c2*64 + l*4]);
      v4f x3 = bf16x4_to_f32(*(const v4u16*)&g[(size_t)c3*64 + l*4]);
      float m0 = (j0+0 < rem) ? 1.f : 0.f;
      float m1 = (j0+1 < rem) ? 1.f : 0.f;
      float m2 = (j0+2 < rem) ? 1.f : 0.f;
      float m3 = (j0+3 < rem) ? 1.f : 0.f;
      acc.x = fmaf(m0,x0.x, fmaf(m1,x1.x, fmaf(m2,x2.x, fmaf(m3,x3.x, acc.x))));
      acc.y = fmaf(m0,x0.y, fmaf(m1,x1.y, fmaf(m2,x2.y, fmaf(m3,x3.y, acc.y))));
      acc.z = fmaf(m0,x0.z, fmaf(m1,x1.z, fmaf(m2,x2.z, fmaf(m3,x3.z, acc.z))));
      acc.w = fmaf(m0,x0.w, fmaf(m1,x1.w, fmaf(m2,x2.w, fmaf(m3,x3.w, acc.w))));
    }
  }
  return acc;
}

// Fused agg + next-layer linear: h = relu(dinv*gather + b) stays on-chip
// (registers -> 4KB LDS), then g2[n,:] = bf16(dinv[n] * (h[n,:] @ W[64,64])).
// 16 nodes/block; matmul: lane = output feature, W row reads are 256B
// coalesced L1-hits, h reads are same-address LDS broadcasts.
__global__ __launch_bounds__(256) void agg_lin_kernel(const unsigned short* __restrict__ g,
                                                      const int* __restrict__ row_ptr,
                                                      const int* __restrict__ col,
                                                      const float* __restrict__ dinv,
                                                      const float* __restrict__ bias,
                                                      const float* __restrict__ W,
                                                      unsigned short* __restrict__ g2,
                                                      int N){
  __shared__ __align__(16) float hsh[16*64];
  int t = threadIdx.x, wave = t>>6, lane = t&63;
  int l = lane & 15, q = lane >> 4;
  int n = blockIdx.x*16 + wave*4 + q;
  bool valid = n < N;
  int nn = valid ? n : (N-1);
  int s = row_ptr[nn], e = row_ptr[nn+1];
  v4f acc = gather_row4(g, col, nn, s, e, l);
  float dv = dinv[nn];
  v4f bs = *(const v4f*)&bias[l*4];
  v4f hv;
  hv.x = fmaxf(fmaf(dv, acc.x, bs.x), 0.f);
  hv.y = fmaxf(fmaf(dv, acc.y, bs.y), 0.f);
  hv.z = fmaxf(fmaf(dv, acc.z, bs.z), 0.f);
  hv.w = fmaxf(fmaf(dv, acc.w, bs.w), 0.f);
  *(v4f*)&hsh[(wave*4+q)*64 + l*4] = hv;
  __syncthreads();
  // ---- h @ W for this wave's 4 nodes; lane = output feature j ----
  const float* hrow = &hsh[wave*4*64];
  float o0=0.f, o1=0.f, o2=0.f, o3=0.f;
  #pragma unroll 4
  for(int k=0;k<64;k++){
    float w = W[k*64 + lane];
    o0 = fmaf(hrow[k],       w, o0);
    o1 = fmaf(hrow[64+k],    w, o1);
    o2 = fmaf(hrow[128+k],   w, o2);
    o3 = fmaf(hrow[192+k],   w, o3);
  }
  int base = blockIdx.x*16 + wave*4;
  if(base+0 < N) g2[(size_t)(base+0)*64 + lane] = f32_to_bf16(dinv[base+0]*o0);
  if(base+1 < N) g2[(size_t)(base+1)*64 + lane] = f32_to_bf16(dinv[base+1]*o1);
  if(base+2 < N) g2[(size_t)(base+2)*64 + lane] = f32_to_bf16(dinv[base+2]*o2);
  if(base+3 < N) g2[(size_t)(base+3)*64 + lane] = f32_to_bf16(dinv[base+3]*o3);
}

// Layer-3 agg with fused FC + log_softmax epilogue: never materializes h3.
__global__ __launch_bounds__(256) void agg_final_kernel(const unsigned short* __restrict__ g,
                                                        const int* __restrict__ row_ptr,
                                                        const int* __restrict__ col,
                                                        const float* __restrict__ dinv,
                                                        const float* __restrict__ bias,
                                                        const float* __restrict__ Wfc,
                                                        const float* __restrict__ bfc,
                                                        float* __restrict__ out, int N){
  int t = threadIdx.x, wave = t>>6, lane = t&63;
  int l = lane & 15, q = lane >> 4;
  int n = blockIdx.x*16 + wave*4 + q;
  bool valid = n < N;
  if(!valid) n = N-1;
  int s = row_ptr[n], e = row_ptr[n+1];
  v4f acc = gather_row4(g, col, n, s, e, l);
  float dv = dinv[n];
  v4f bs = *(const v4f*)&bias[l*4];
  v4f hv;
  hv.x = fmaxf(fmaf(dv, acc.x, bs.x), 0.f);
  hv.y = fmaxf(fmaf(dv, acc.y, bs.y), 0.f);
  hv.z = fmaxf(fmaf(dv, acc.z, bs.z), 0.f);
  hv.w = fmaxf(fmaf(dv, acc.w, bs.w), 0.f);
  // Wfc row-major [64][2]: lane l covers features 4l..4l+3 -> 8 floats at 8l.
  v4f wa = *(const v4f*)&Wfc[l*8];
  v4f wb = *(const v4f*)&Wfc[l*8+4];
  float p0 = hv.x*wa.x + hv.y*wa.z + hv.z*wb.x + hv.w*wb.z;
  float p1 = hv.x*wa.y + hv.y*wa.w + hv.z*wb.y + hv.w*wb.w;
  for(int off=8; off; off>>=1){
    p0 += __shfl_down(p0, off, 16);
    p1 += __shfl_down(p1, off, 16);
  }
  if(valid && l==0){
    float l0 = p0 + bfc[0], l1 = p1 + bfc[1];
    float m  = fmaxf(l0, l1);
    float lse = m + logf(expf(l0-m) + expf(l1-m));
    out[(size_t)n*2+0] = l0 - lse;
    out[(size_t)n*2+1] = l1 - lse;
  }
}

extern "C" void kernel_launch(void* const* d_in, const int* in_sizes, int n_in,
                              void* d_out, int out_size, void* d_ws, size_t ws_size,
                              hipStream_t stream) {
  (void)n_in; (void)out_size; (void)ws_size;
  const float* x   = (const float*)d_in[0];
  const int*   ei  = (const int*)  d_in[1];
  const float* W1  = (const float*)d_in[2];
  const float* b1  = (const float*)d_in[3];
  const float* W2  = (const float*)d_in[4];
  const float* b2  = (const float*)d_in[5];
  const float* W3  = (const float*)d_in[6];
  const float* b3  = (const float*)d_in[7];
  const float* Wfc = (const float*)d_in[8];
  const float* bfc = (const float*)d_in[9];
  float* out = (float*)d_out;

  const int N = in_sizes[0] / 128;   // 100000
  const int E = in_sizes[1] / 2;     // 1600000
  const int* src = ei;
  const int* dst = ei + E;
  const int NB = (N + 127) / 128;    // 782 buckets

  // ---- workspace carve ----
  char* w = (char*)d_ws;
  int*   bcnt    = (int*)  w; w += alignup((size_t)NBUCK*4);
  int*   bbase   = (int*)  w; w += alignup((size_t)(NBUCK+1)*4);
  int*   bfill   = (int*)  w; w += alignup((size_t)NBUCK*4);
  int*   pairs   = (int*)  w; w += alignup((size_t)E*4);
  int*   row_ptr = (int*)  w; w += alignup((size_t)(N+1)*4);
  float* dinv    = (float*)w; w += alignup((size_t)N*4);
  int*   col     = (int*)  w; w += alignup((size_t)E*4);
  unsigned short* gA = (unsigned short*)w; w += alignup((size_t)N*64*2); // bf16
  unsigned short* gB = (unsigned short*)w; w += alignup((size_t)N*64*2); // bf16

  const int nblkE   = (E + CHUNK - 1) / CHUNK;   // 196
  const int nblkLin = (N + 31) / 32;             // TR=32 -> 3125 (exact)
  const int nblkAgg = (N + 15) / 16;             // 4 nodes/wave, 4 waves/blk

  // ---- CSR build ----
  zero_kernel<<<(NBUCK+255)/256, 256, 0, stream>>>(bcnt, NBUCK);
  hist_kernel<<<nblkE, 256, 0, stream>>>(dst, bcnt, E);
  scan_buckets_kernel<<<1, 256, 0, stream>>>(bcnt, bbase, bfill);
  scatter_kernel<<<nblkE, 256, 0, stream>>>(src, dst, bfill, pairs, E);
  bucket_csr_kernel<<<NB, 256, 0, stream>>>(pairs, bbase, row_ptr, dinv, col, N, E);

  // ---- layer 1 linear: x[N,128] -> gA ----
  lin_kernel<128><<<nblkLin, 256, 0, stream>>>(x, W1, dinv, gA, N);
  // ---- agg1 + lin2 fused: gA -> gB ----
  agg_lin_kernel<<<nblkAgg, 256, 0, stream>>>(gA, row_ptr, col, dinv, b1, W2, gB, N);
  // ---- agg2 + lin3 fused: gB -> gA ----
  agg_lin_kernel<<<nblkAgg, 256, 0, stream>>>(gB, row_ptr, col, dinv, b2, W3, gA, N);
  // ---- agg3 + FC + log_softmax (fused): gA -> out ----
  agg_final_kernel<<<nblkAgg, 256, 0, stream>>>(gA, row_ptr, col, dinv, b3,
                                                Wfc, bfc, out, N);
}

// Round 14
// 318.915 us; speedup vs baseline: 2.2095x; 1.0216x over previous
//
#include <hip/hip_runtime.h>
#include <math.h>

// ---------------------------------------------------------------------------
// FraudDetectionGCN: 3x GCNConv(relu) + FC + log_softmax.
// R14 changes vs R13 (CSR build had ~110us hidden, write-amplified):
//  * scatter: LDS presort (hist -> in-block scan -> global base reservation
//    (4 pipelined atomics/thread) -> LDS placement sorted by bucket ->
//    copy-out with consecutive addresses per run). Kills the 69MB partial-
//    line RMW write amplification seen in R12's counters.
//  * bucket_csr: reverted to R11's LDS-staged form (contiguous col writes) —
//    R12/R13's direct random 4B col writes re-introduced amplification.
//  * agg gather: reinstated 4-granular early break (R10) — masked full-16
//    processing wasted ~47% issue/latency at mean degree 16.
// agg: bf16 g rows; norm factorization:
// out[n] = dinv[n]*(sum_{s->n} g[s] + g[n]) + b, g = dinv[:,None]*(h@W).
// ---------------------------------------------------------------------------

static inline size_t alignup(size_t x){ return (x + 511) & ~size_t(511); }

typedef float v4f __attribute__((ext_vector_type(4)));
typedef unsigned short v4u16 __attribute__((ext_vector_type(4)));

__device__ __forceinline__ unsigned short f32_to_bf16(float f){
  union { float f; unsigned int u; } c; c.f = f;
  unsigned int u = c.u + 0x7FFFu + ((c.u >> 16) & 1u);   // round-nearest-even
  return (unsigned short)(u >> 16);
}
__device__ __forceinline__ v4f bf16x4_to_f32(v4u16 a){
  union { unsigned int u; float f; } c0,c1,c2,c3;
  c0.u = (unsigned int)a.x << 16;
  c1.u = (unsigned int)a.y << 16;
  c2.u = (unsigned int)a.z << 16;
  c3.u = (unsigned int)a.w << 16;
  v4f r; r.x=c0.f; r.y=c1.f; r.z=c2.f; r.w=c3.f;
  return r;
}

#define NBUCK 1024          // histogram bins (dst>>7); 782 used at N=100k
#define CHUNK 8192          // edges per block in hist/scatter (196 blocks)
#define CCAP  3584          // max edges per bucket (mean ~2046, +30 sigma)

__global__ void zero_kernel(int* __restrict__ p, int n){
  int i = blockIdx.x*256 + threadIdx.x;
  if(i<n) p[i] = 0;
}

// Pass A: global histogram of dst>>7 (LDS-aggregated).
__global__ __launch_bounds__(256) void hist_kernel(const int* __restrict__ dst,
                                                   int* __restrict__ bcnt, int E){
  __shared__ int h[NBUCK];
  int t = threadIdx.x;
  for(int i=t;i<NBUCK;i+=256) h[i]=0;
  __syncthreads();
  int base = blockIdx.x*CHUNK;
  #pragma unroll 4
  for(int i=0;i<CHUNK;i+=256){
    int e = base+i+t;
    if(e<E) atomicAdd(&h[dst[e]>>7], 1);
  }
  __syncthreads();
  for(int i=t;i<NBUCK;i+=256) if(h[i]) atomicAdd(&bcnt[i], h[i]);
}

// Exclusive scan of 1024 bucket counts (single block). bbase = bfill = prefix.
__global__ void scan_buckets_kernel(const int* __restrict__ bcnt, int* __restrict__ bbase,
                                    int* __restrict__ bfill){
  __shared__ int sh[256];
  int t = threadIdx.x;
  int v0=bcnt[4*t], v1=bcnt[4*t+1], v2=bcnt[4*t+2], v3=bcnt[4*t+3];
  int ts = v0+v1+v2+v3;
  sh[t]=ts; __syncthreads();
  for(int off=1; off<256; off<<=1){
    int x=(t>=off)?sh[t-off]:0; __syncthreads();
    sh[t]+=x; __syncthreads();
  }
  int run = sh[t]-ts;
  int i0=4*t;
  bbase[i0+0]=run; bfill[i0+0]=run; run+=v0;
  bbase[i0+1]=run; bfill[i0+1]=run; run+=v1;
  bbase[i0+2]=run; bfill[i0+2]=run; run+=v2;
  bbase[i0+3]=run; bfill[i0+3]=run;
}

// Pass B: scatter packed (local_dst<<17 | src) into bucket regions,
// LDS-presorted so global writes are dense runs (no partial-line RMW thrash).
__global__ __launch_bounds__(256) void scatter_kernel(const int* __restrict__ src,
                                                      const int* __restrict__ dst,
                                                      int* __restrict__ bfill,
                                                      int* __restrict__ pairs, int E){
  __shared__ int hist[NBUCK];            // counts -> reused as fill counters
  __shared__ int delta[NBUCK];           // gbase - lstart per bucket
  __shared__ int sh[256];
  __shared__ int vals[CHUNK];            // 32KB sorted-by-bucket payloads
  __shared__ unsigned short bkt[CHUNK];  // 16KB bucket id per slot
  int t = threadIdx.x;
  int cbase = blockIdx.x*CHUNK;
  for(int i=t;i<NBUCK;i+=256) hist[i]=0;
  __syncthreads();
  // A: local histogram
  #pragma unroll 4
  for(int i=0;i<CHUNK;i+=256){
    int e = cbase+i+t;
    if(e<E) atomicAdd(&hist[dst[e]>>7], 1);
  }
  __syncthreads();
  // B: in-block exclusive scan (4 bins/thread) + global base reservation
  int i0 = 4*t;
  int v0=hist[i0], v1=hist[i0+1], v2=hist[i0+2], v3=hist[i0+3];
  int ts = v0+v1+v2+v3;
  sh[t]=ts; __syncthreads();
  for(int off=1; off<256; off<<=1){
    int x=(t>=off)?sh[t-off]:0; __syncthreads();
    sh[t]+=x; __syncthreads();
  }
  int run = sh[t]-ts;
  int g0 = v0 ? atomicAdd(&bfill[i0+0], v0) : 0;
  int g1 = v1 ? atomicAdd(&bfill[i0+1], v1) : 0;
  int g2 = v2 ? atomicAdd(&bfill[i0+2], v2) : 0;
  int g3 = v3 ? atomicAdd(&bfill[i0+3], v3) : 0;
  int l0=run, l1=run+v0, l2=l1+v1, l3=l2+v2;
  __syncthreads();                      // everyone done reading hist counts
  hist[i0+0]=l0; delta[i0+0]=g0-l0;     // hist becomes fill counter
  hist[i0+1]=l1; delta[i0+1]=g1-l1;
  hist[i0+2]=l2; delta[i0+2]=g2-l2;
  hist[i0+3]=l3; delta[i0+3]=g3-l3;
  __syncthreads();
  // C: place into LDS sorted by bucket
  #pragma unroll 4
  for(int i=0;i<CHUNK;i+=256){
    int e = cbase+i+t;
    if(e<E){
      int d = dst[e];
      int b = d>>7;
      int slot = atomicAdd(&hist[b], 1);
      vals[slot] = ((d&127)<<17) | src[e];
      bkt[slot]  = (unsigned short)b;
    }
  }
  __syncthreads();
  // D: dense copy-out (addresses consecutive within each run)
  int cnt = E - cbase; if(cnt > CHUNK) cnt = CHUNK;
  for(int i=t;i<cnt;i+=256){
    int b = bkt[i];
    pairs[delta[b] + i] = vals[i];
  }
}

// Pass C: one block per bucket (128 dst nodes). LDS counting sort ->
// row_ptr, dinv, srcs staged in LDS -> fully-contiguous col writes.
__global__ __launch_bounds__(256) void bucket_csr_kernel(const int* __restrict__ pairs,
                                                         const int* __restrict__ bbase,
                                                         int* __restrict__ row_ptr,
                                                         float* __restrict__ dinv,
                                                         int* __restrict__ col,
                                                         int N, int E){
  __shared__ int hist[128];
  __shared__ int pref[128];
  __shared__ int fill[128];
  __shared__ int srcs[CCAP];
  int b = blockIdx.x, t = threadIdx.x;
  int s = bbase[b], e = bbase[b+1];
  int cnt = e - s; if(cnt > CCAP) cnt = CCAP;   // unreachable guard
  if(t<128) hist[t]=0;
  __syncthreads();
  int v[CCAP/256];
  #pragma unroll
  for(int i=0;i<CCAP/256;i++){
    int idx = i*256 + t;
    if(idx<cnt){ v[i]=pairs[s+idx]; atomicAdd(&hist[v[i]>>17], 1); }
  }
  __syncthreads();
  if(t<128) pref[t]=hist[t];
  __syncthreads();
  for(int off=1; off<128; off<<=1){
    int x=0;
    if(t<128 && t>=off) x=pref[t-off];
    __syncthreads();
    if(t<128) pref[t]+=x;
    __syncthreads();
  }
  if(t<128){
    int ex = pref[t]-hist[t];                 // exclusive prefix
    fill[t]=ex;
    int node = b*128 + t;
    if(node<N){
      row_ptr[node] = s + ex;
      dinv[node] = rsqrtf((float)(hist[t]+1)); // +1 self loop
    }
  }
  if(b==0 && t==0) row_ptr[N]=E;
  __syncthreads();
  #pragma unroll
  for(int i=0;i<CCAP/256;i++){
    int idx = i*256 + t;
    if(idx<cnt){
      int ld = v[i]>>17;
      int pos = atomicAdd(&fill[ld], 1);
      srcs[pos] = v[i] & 0x1FFFF;
    }
  }
  __syncthreads();
  for(int i=t;i<cnt;i+=256) col[s+i]=srcs[i];   // contiguous
}

// g[n,:] = bf16( dinv[n] * (h[n,:K] @ W[K,64]) ).  Layer 1 only.
// LDS-staged: TR=32 rows, 4 waves x RW=8 rows; k-unroll 2 (R7 spill lesson).
template<int K>
__global__ __launch_bounds__(256) void lin_kernel(const float* __restrict__ h,
                                                  const float* __restrict__ W,
                                                  const float* __restrict__ dinv,
                                                  unsigned short* __restrict__ g, int N){
  constexpr int TR = 32, RW = 8;
  __shared__ __align__(16) float hs[TR*K];
  int t = threadIdx.x, wave = t>>6, lane = t&63;
  long rbase = (long)blockIdx.x*TR;
  const v4f* hsrc = (const v4f*)(h + rbase*K);
  if(rbase + TR <= N){
    #pragma unroll
    for(int idx = t; idx < TR*K/4; idx += 256)
      ((v4f*)hs)[idx] = hsrc[idx];
  } else {
    int lim = (int)((N - rbase)*K/4);            // tail block
    for(int idx = t; idx < lim; idx += 256)
      ((v4f*)hs)[idx] = hsrc[idx];
  }
  __syncthreads();
  float acc[RW];
  #pragma unroll
  for(int r=0;r<RW;r++) acc[r]=0.f;
  const float* hw = hs + wave*RW*K;
  #pragma unroll 2
  for(int k=0;k<K;k+=4){
    float w0 = W[(k+0)*64+lane];
    float w1 = W[(k+1)*64+lane];
    float w2 = W[(k+2)*64+lane];
    float w3 = W[(k+3)*64+lane];
    #pragma unroll
    for(int r=0;r<RW;r++){
      v4f hv = *(const v4f*)&hw[r*K+k];
      acc[r] = fmaf(hv.w, w3, fmaf(hv.z, w2, fmaf(hv.y, w1, fmaf(hv.x, w0, acc[r]))));
    }
  }
  long row0 = rbase + wave*RW;
  #pragma unroll
  for(int r=0;r<RW;r++){
    if(row0 + r < N)
      g[(row0+r)*64 + lane] = f32_to_bf16(dinv[row0+r]*acc[r]);
  }
}

// Gather for 4-nodes-per-wave layout over bf16 g rows (128B each):
// lane = 16*q + l; group q handles node n, lane carries features [4l,4l+4).
// 4-granular early break (group-uniform) avoids masked-slot waste; fp32 accum.
__device__ __forceinline__ v4f gather_row4(const unsigned short* __restrict__ g,
                                           const int* __restrict__ col,
                                           int n, int s, int e, int l){
  v4f acc = bf16x4_to_f32(*(const v4u16*)&g[(size_t)n*64 + l*4]);   // self
  for(int i = s; i < e; i += 16){
    int rem = e - i;                               // group-uniform
    int myc = (l < rem) ? col[i + l] : n;
    #pragma unroll
    for(int j0 = 0; j0 < 16; j0 += 4){
      int c0 = __shfl(myc, j0+0, 16);
      int c1 = __shfl(myc, j0+1, 16);
      int c2 = __shfl(myc, j0+2, 16);
      int c3 = __shfl(myc, j0+3, 16);
      v4f x0 = bf16x4_to_f32(*(const v4u16*)&g[(size_t)c0*64 + l*4]);
      v4f x1 = bf16x4_to_f32(*(const v4u16*)&g[(size_t)c1*64 + l*4]);
      v4f x2 = bf16x4_to_f32(*(const v4u16*)&g[(size_t)c2*64 + l*4]);
      v4f x3 = bf16x4_to_f32(*(const v4u16*)&g[(size_t)c3*64 + l*4]);
      float m0 = (j0+0 < rem) ? 1.f : 0.f;
      float m1 = (j0+1 < rem) ? 1.f : 0.f;
      float m2 = (j0+2 < rem) ? 1.f : 0.f;
      float m3 = (j0+3 < rem) ? 1.f : 0.f;
      acc.x = fmaf(m0,x0.x, fmaf(m1,x1.x, fmaf(m2,x2.x, fmaf(m3,x3.x, acc.x))));
      acc.y = fmaf(m0,x0.y, fmaf(m1,x1.y, fmaf(m2,x2.y, fmaf(m3,x3.y, acc.y))));
      acc.z = fmaf(m0,x0.z, fmaf(m1,x1.z, fmaf(m2,x2.z, fmaf(m3,x3.z, acc.z))));
      acc.w = fmaf(m0,x0.w, fmaf(m1,x1.w, fmaf(m2,x2.w, fmaf(m3,x3.w, acc.w))));
      if(j0+4 >= rem) break;                       // group-uniform early out
    }
  }
  return acc;
}

// Fused agg + next-layer linear: h = relu(dinv*gather + b) stays on-chip
// (registers -> 4KB LDS), then g2[n,:] = bf16(dinv[n] * (h[n,:] @ W[64,64])).
__global__ __launch_bounds__(256) void agg_lin_kernel(const unsigned short* __restrict__ g,
                                                      const int* __restrict__ row_ptr,
                                                      const int* __restrict__ col,
                                                      const float* __restrict__ dinv,
                                                      const float* __restrict__ bias,
                                                      const float* __restrict__ W,
                                                      unsigned short* __restrict__ g2,
                                                      int N){
  __shared__ __align__(16) float hsh[16*64];
  int t = threadIdx.x, wave = t>>6, lane = t&63;
  int l = lane & 15, q = lane >> 4;
  int n = blockIdx.x*16 + wave*4 + q;
  bool valid = n < N;
  int nn = valid ? n : (N-1);
  int s = row_ptr[nn], e = row_ptr[nn+1];
  v4f acc = gather_row4(g, col, nn, s, e, l);
  float dv = dinv[nn];
  v4f bs = *(const v4f*)&bias[l*4];
  v4f hv;
  hv.x = fmaxf(fmaf(dv, acc.x, bs.x), 0.f);
  hv.y = fmaxf(fmaf(dv, acc.y, bs.y), 0.f);
  hv.z = fmaxf(fmaf(dv, acc.z, bs.z), 0.f);
  hv.w = fmaxf(fmaf(dv, acc.w, bs.w), 0.f);
  *(v4f*)&hsh[(wave*4+q)*64 + l*4] = hv;
  __syncthreads();
  // ---- h @ W for this wave's 4 nodes; lane = output feature j ----
  const float* hrow = &hsh[wave*4*64];
  float o0=0.f, o1=0.f, o2=0.f, o3=0.f;
  #pragma unroll 4
  for(int k=0;k<64;k++){
    float w = W[k*64 + lane];
    o0 = fmaf(hrow[k],       w, o0);
    o1 = fmaf(hrow[64+k],    w, o1);
    o2 = fmaf(hrow[128+k],   w, o2);
    o3 = fmaf(hrow[192+k],   w, o3);
  }
  int base = blockIdx.x*16 + wave*4;
  if(base+0 < N) g2[(size_t)(base+0)*64 + lane] = f32_to_bf16(dinv[base+0]*o0);
  if(base+1 < N) g2[(size_t)(base+1)*64 + lane] = f32_to_bf16(dinv[base+1]*o1);
  if(base+2 < N) g2[(size_t)(base+2)*64 + lane] = f32_to_bf16(dinv[base+2]*o2);
  if(base+3 < N) g2[(size_t)(base+3)*64 + lane] = f32_to_bf16(dinv[base+3]*o3);
}

// Layer-3 agg with fused FC + log_softmax epilogue: never materializes h3.
__global__ __launch_bounds__(256) void agg_final_kernel(const unsigned short* __restrict__ g,
                                                        const int* __restrict__ row_ptr,
                                                        const int* __restrict__ col,
                                                        const float* __restrict__ dinv,
                                                        const float* __restrict__ bias,
                                                        const float* __restrict__ Wfc,
                                                        const float* __restrict__ bfc,
                                                        float* __restrict__ out, int N){
  int t = threadIdx.x, wave = t>>6, lane = t&63;
  int l = lane & 15, q = lane >> 4;
  int n = blockIdx.x*16 + wave*4 + q;
  bool valid = n < N;
  if(!valid) n = N-1;
  int s = row_ptr[n], e = row_ptr[n+1];
  v4f acc = gather_row4(g, col, n, s, e, l);
  float dv = dinv[n];
  v4f bs = *(const v4f*)&bias[l*4];
  v4f hv;
  hv.x = fmaxf(fmaf(dv, acc.x, bs.x), 0.f);
  hv.y = fmaxf(fmaf(dv, acc.y, bs.y), 0.f);
  hv.z = fmaxf(fmaf(dv, acc.z, bs.z), 0.f);
  hv.w = fmaxf(fmaf(dv, acc.w, bs.w), 0.f);
  // Wfc row-major [64][2]: lane l covers features 4l..4l+3 -> 8 floats at 8l.
  v4f wa = *(const v4f*)&Wfc[l*8];
  v4f wb = *(const v4f*)&Wfc[l*8+4];
  float p0 = hv.x*wa.x + hv.y*wa.z + hv.z*wb.x + hv.w*wb.z;
  float p1 = hv.x*wa.y + hv.y*wa.w + hv.z*wb.y + hv.w*wb.w;
  for(int off=8; off; off>>=1){
    p0 += __shfl_down(p0, off, 16);
    p1 += __shfl_down(p1, off, 16);
  }
  if(valid && l==0){
    float l0 = p0 + bfc[0], l1 = p1 + bfc[1];
    float m  = fmaxf(l0, l1);
    float lse = m + logf(expf(l0-m) + expf(l1-m));
    out[(size_t)n*2+0] = l0 - lse;
    out[(size_t)n*2+1] = l1 - lse;
  }
}

extern "C" void kernel_launch(void* const* d_in, const int* in_sizes, int n_in,
                              void* d_out, int out_size, void* d_ws, size_t ws_size,
                              hipStream_t stream) {
  (void)n_in; (void)out_size; (void)ws_size;
  const float* x   = (const float*)d_in[0];
  const int*   ei  = (const int*)  d_in[1];
  const float* W1  = (const float*)d_in[2];
  const float* b1  = (const float*)d_in[3];
  const float* W2  = (const float*)d_in[4];
  const float* b2  = (const float*)d_in[5];
  const float* W3  = (const float*)d_in[6];
  const float* b3  = (const float*)d_in[7];
  const float* Wfc = (const float*)d_in[8];
  const float* bfc = (const float*)d_in[9];
  float* out = (float*)d_out;

  const int N = in_sizes[0] / 128;   // 100000
  const int E = in_sizes[1] / 2;     // 1600000
  const int* src = ei;
  const int* dst = ei + E;
  const int NB = (N + 127) / 128;    // 782 buckets

  // ---- workspace carve ----
  char* w = (char*)d_ws;
  int*   bcnt    = (int*)  w; w += alignup((size_t)NBUCK*4);
  int*   bbase   = (int*)  w; w += alignup((size_t)(NBUCK+1)*4);
  int*   bfill   = (int*)  w; w += alignup((size_t)NBUCK*4);
  int*   pairs   = (int*)  w; w += alignup((size_t)E*4);
  int*   row_ptr = (int*)  w; w += alignup((size_t)(N+1)*4);
  float* dinv    = (float*)w; w += alignup((size_t)N*4);
  int*   col     = (int*)  w; w += alignup((size_t)E*4);
  unsigned short* gA = (unsigned short*)w; w += alignup((size_t)N*64*2); // bf16
  unsigned short* gB = (unsigned short*)w; w += alignup((size_t)N*64*2); // bf16

  const int nblkE   = (E + CHUNK - 1) / CHUNK;   // 196
  const int nblkLin = (N + 31) / 32;             // TR=32 -> 3125 (exact)
  const int nblkAgg = (N + 15) / 16;             // 4 nodes/wave, 4 waves/blk

  // ---- CSR build ----
  zero_kernel<<<(NBUCK+255)/256, 256, 0, stream>>>(bcnt, NBUCK);
  hist_kernel<<<nblkE, 256, 0, stream>>>(dst, bcnt, E);
  scan_buckets_kernel<<<1, 256, 0, stream>>>(bcnt, bbase, bfill);
  scatter_kernel<<<nblkE, 256, 0, stream>>>(src, dst, bfill, pairs, E);
  bucket_csr_kernel<<<NB, 256, 0, stream>>>(pairs, bbase, row_ptr, dinv, col, N, E);

  // ---- layer 1 linear: x[N,128] -> gA ----
  lin_kernel<128><<<nblkLin, 256, 0, stream>>>(x, W1, dinv, gA, N);
  // ---- agg1 + lin2 fused: gA -> gB ----
  agg_lin_kernel<<<nblkAgg, 256, 0, stream>>>(gA, row_ptr, col, dinv, b1, W2, gB, N);
  // ---- agg2 + lin3 fused: gB -> gA ----
  agg_lin_kernel<<<nblkAgg, 256, 0, stream>>>(gB, row_ptr, col, dinv, b2, W3, gA, N);
  // ---- agg3 + FC + log_softmax (fused): gA -> out ----
  agg_final_kernel<<<nblkAgg, 256, 0, stream>>>(gA, row_ptr, col, dinv, b3,
                                                Wfc, bfc, out, N);
}